// Round 7
// baseline (542.425 us; speedup 1.0000x reference)
//
#include <hip/hip_runtime.h>
#include <hip/hip_fp16.h>

// Problem constants (B=1 fixed)
#define CC   32
#define DD   24
#define HH   96
#define WW   96
#define HWC  (HH*WW)        // 9216
#define DHW  (DD*HH*WW)     // 221184
#define NG   4
#define CPG  (CC/NG)        // 8
#define OC1  54
#define GN_EPS 1e-5f

#define NBLK_O (DHW/128)    // 1728 (offs: 128 pts/block)
#define CHUNK_O (NBLK_O/8)  // 216
#define NBLK_D (DHW/64)     // 3456 (deform: 64 pts/block, 2 tap-split waves)
#define CHUNK_D (NBLK_D/8)  // 432
#define NBLK_G (DHW/256)    // 864  (gn_apply)
#define CHUNK_G (NBLK_G/8)  // 108

typedef float  f32x4 __attribute__((ext_vector_type(4)));
typedef _Float16 f16x8 __attribute__((ext_vector_type(8)));
typedef unsigned int u32x4 __attribute__((ext_vector_type(4)));

union F16Frag { f16x8 v; __half2 h2[4]; };

// XCD-chunked swizzle: block b -> XCD b%8 gets a contiguous chunk, so every
// kernel's XCD k owns the SAME 27648-point slice (producer/consumer L2 match).
__device__ __forceinline__ int swz(int bid, int chunk) {
    return (bid % 8) * chunk + (bid / 8);
}

// ---- pack weights into per-tap MFMA B-fragments ----
// src: [O][CC][27] fp32. dst: [tap][nt][lane][e] f16, o=nt*16+(lane&15), c=(lane>>4)*8+e.
__global__ void pack_w(const float* __restrict__ src, _Float16* __restrict__ dst,
                       int O, int NT, int n) {
    int idx = blockIdx.x * 256 + threadIdx.x;
    if (idx >= n) return;
    int e    = idx & 7;
    int lane = (idx >> 3) & 63;
    int nt   = (idx >> 9) % NT;
    int tap  = (idx >> 9) / NT;
    int o = nt * 16 + (lane & 15);
    int c = (lane >> 4) * 8 + e;
    float v = (o < O) ? src[(o * CC + c) * 27 + tap] : 0.f;
    dst[idx] = (_Float16)v;
}

// ---- group-norm stats ----
__global__ void gn_stats(const float* __restrict__ x, float* __restrict__ stats) {
    const int g = blockIdx.x >> 5;
    const int s = blockIdx.x & 31;
    const float4* base = (const float4*)(x + (size_t)g * CPG * DHW);
    const int n4 = CPG * DHW / 4;
    float s1 = 0.f, s2 = 0.f;
    for (int idx = s * 256 + threadIdx.x; idx < n4; idx += 32 * 256) {
        float4 v = base[idx];
        s1 += v.x + v.y + v.z + v.w;
        s2 += v.x * v.x + v.y * v.y + v.z * v.z + v.w * v.w;
    }
    for (int off = 32; off > 0; off >>= 1) {
        s1 += __shfl_down(s1, off);
        s2 += __shfl_down(s2, off);
    }
    __shared__ float ls1[4], ls2[4];
    int wid = threadIdx.x >> 6;
    if ((threadIdx.x & 63) == 0) { ls1[wid] = s1; ls2[wid] = s2; }
    __syncthreads();
    if (threadIdx.x == 0) {
        float a = 0.f, b = 0.f;
        for (int i = 0; i < 4; i++) { a += ls1[i]; b += ls2[i]; }
        atomicAdd(&stats[g * 2 + 0], a);
        atomicAdd(&stats[g * 2 + 1], b);
    }
}

// ---- group-norm apply + relu + transpose to channels-last f16 ----
__global__ void gn_apply_T(const float* __restrict__ x, const float* __restrict__ stats,
                           const float* __restrict__ gamma, const float* __restrict__ beta,
                           __half* __restrict__ yT) {
    const int p = swz(blockIdx.x, CHUNK_G) * 256 + threadIdx.x;
    const float invN = 1.0f / (float)(CPG * DHW);
    float mean[NG], rstd[NG];
#pragma unroll
    for (int g = 0; g < NG; g++) {
        mean[g] = stats[2 * g] * invN;
        float var = stats[2 * g + 1] * invN - mean[g] * mean[g];
        rstd[g] = rsqrtf(var + GN_EPS);
    }
    float vals[CC];
#pragma unroll
    for (int c = 0; c < CC; c++) {
        const int g = c >> 3;
        const float ga = gamma[c] * rstd[g];
        const float be = beta[c] - mean[g] * ga;
        vals[c] = fmaxf(0.f, x[(size_t)c * DHW + p] * ga + be);
    }
    union { __half2 h2[16]; u32x4 q[4]; } u;
#pragma unroll
    for (int c = 0; c < 16; c++) u.h2[c] = __floats2half2_rn(vals[2 * c], vals[2 * c + 1]);
    u32x4* dst = (u32x4*)(yT + (size_t)p * CC);
#pragma unroll
    for (int q = 0; q < 4; q++) dst[q] = u.q[q];
}

// ---- dense 3x3x3 conv 32->54 via MFMA; offsets out channels-last f16 [p][54] ----
// Verified C/D mapping (round-5): o = nt*16 + (lane&15), point = (lane>>4)*4 + reg.
__global__ __launch_bounds__(128) void offs_mfma(const __half* __restrict__ xT,
                                                 const _Float16* __restrict__ wB,
                                                 const float* __restrict__ bias,
                                                 __half* __restrict__ offC) {
    const int tid  = threadIdx.x;
    const int lane = tid & 63;
    const int wave = tid >> 6;
    const int p0   = swz(blockIdx.x, CHUNK_O) * 128;
    const int pw   = p0 + wave * 64;
    const int d    = pw / HWC;
    const int rem  = pw % HWC;
    const int mrow = lane & 15;
    const int kg   = lane >> 4;

    int hq[4], wq[4];
#pragma unroll
    for (int m = 0; m < 4; m++) {
        int rr = rem + m * 16 + mrow;
        hq[m] = rr / WW; wq[m] = rr % WW;
    }

    f32x4 acc[4][4];
#pragma unroll
    for (int m = 0; m < 4; m++)
#pragma unroll
        for (int n = 0; n < 4; n++) acc[m][n] = (f32x4){0.f, 0.f, 0.f, 0.f};

    const f16x8* wb8 = (const f16x8*)wB;

#pragma unroll 1
    for (int i = 0; i < 3; i++) {
        const int dd = d + i - 1;
        if ((unsigned)dd >= DD) continue;
        const __half* xd = xT + (size_t)dd * HWC * CC;
#pragma unroll 3
        for (int jk = 0; jk < 9; jk++) {
            const int j = jk / 3, k = jk % 3, tap = i * 9 + jk;
            const f16x8 b0 = wb8[(tap * 4 + 0) * 64 + lane];
            const f16x8 b1 = wb8[(tap * 4 + 1) * 64 + lane];
            const f16x8 b2 = wb8[(tap * 4 + 2) * 64 + lane];
            const f16x8 b3 = wb8[(tap * 4 + 3) * 64 + lane];
#pragma unroll
            for (int m = 0; m < 4; m++) {
                const int hh = hq[m] + j - 1;
                const int ww = wq[m] + k - 1;
                f16x8 a = {0, 0, 0, 0, 0, 0, 0, 0};
                if ((unsigned)hh < HH && (unsigned)ww < WW)
                    a = *(const f16x8*)(xd + (size_t)(hh * WW + ww) * CC + kg * 8);
                acc[m][0] = __builtin_amdgcn_mfma_f32_16x16x32_f16(a, b0, acc[m][0], 0, 0, 0);
                acc[m][1] = __builtin_amdgcn_mfma_f32_16x16x32_f16(a, b1, acc[m][1], 0, 0, 0);
                acc[m][2] = __builtin_amdgcn_mfma_f32_16x16x32_f16(a, b2, acc[m][2], 0, 0, 0);
                acc[m][3] = __builtin_amdgcn_mfma_f32_16x16x32_f16(a, b3, acc[m][3], 0, 0, 0);
            }
        }
    }

    // stage f16, o-major [o][136 pts]: lane's acc[m][nt] = 4 consecutive POINTS
    // (m*16 + kg*4 + r) at single o = nt*16 + mrow  (verified D mapping).
    __shared__ __half lds_h[OC1 * 136];
#pragma unroll
    for (int m = 0; m < 4; m++) {
#pragma unroll
        for (int nt = 0; nt < 4; nt++) {
            const int o = nt * 16 + mrow;
            if (o < OC1) {
                const int idx = o * 136 + wave * 64 + m * 16 + kg * 4;
                __half2 lo = __floats2half2_rn(acc[m][nt].x, acc[m][nt].y);
                __half2 hi = __floats2half2_rn(acc[m][nt].z, acc[m][nt].w);
                *(__half2*)&lds_h[idx]     = lo;
                *(__half2*)&lds_h[idx + 2] = hi;
            }
        }
    }
    __syncthreads();
    // copy-out: thread = point; add bias fp32; 27 u32 (54 halves) contiguous
    unsigned int* dst = (unsigned int*)(offC + (size_t)(p0 + tid) * 54);
#pragma unroll 1
    for (int o2 = 0; o2 < 27; o2++) {
        float f0 = __half2float(lds_h[(2 * o2 + 0) * 136 + tid]) + bias[2 * o2 + 0];
        float f1 = __half2float(lds_h[(2 * o2 + 1) * 136 + tid]) + bias[2 * o2 + 1];
        __half2 r = __floats2half2_rn(f0, f1);
        dst[o2] = *(unsigned int*)&r;
    }
}

// ---- deformable conv via MFMA; 2 waves tap-split over same 64 points ----
__global__ __launch_bounds__(128, 6) void deform_mfma(const __half* __restrict__ xT,
                                                      const __half* __restrict__ offC,
                                                      const _Float16* __restrict__ wB,
                                                      const float* __restrict__ bias,
                                                      const float* __restrict__ resid,
                                                      float* __restrict__ outp) {
    const int tid  = threadIdx.x;
    const int lane = tid & 63;
    const int wave = tid >> 6;
    const int p0   = swz(blockIdx.x, CHUNK_D) * 64;
    const int d    = p0 / HWC;
    const int rem  = p0 % HWC;
    const int mrow = lane & 15;
    const int kg   = lane >> 4;

    int hq[4], wq[4];
#pragma unroll
    for (int m = 0; m < 4; m++) {
        int rr = rem + m * 16 + mrow;
        hq[m] = rr / WW; wq[m] = rr % WW;
    }

    f32x4 acc[4][2];
#pragma unroll
    for (int m = 0; m < 4; m++) {
        acc[m][0] = (f32x4){0.f, 0.f, 0.f, 0.f};
        acc[m][1] = (f32x4){0.f, 0.f, 0.f, 0.f};
    }

    const f16x8* wb8 = (const f16x8*)wB;

#pragma unroll 1
    for (int t3 = wave; t3 < 27; t3 += 2) {   // wave0: even taps, wave1: odd taps
        const int i = t3 / 9;
        const int dd = d + i - 1;
        if ((unsigned)dd >= DD) continue;
        const int jk = t3 % 9;
        const int j = jk / 3, k = jk % 3;
        const __half* xd = xT + (size_t)dd * HWC * CC;
        const f16x8 b0 = wb8[(t3 * 2 + 0) * 64 + lane];
        const f16x8 b1 = wb8[(t3 * 2 + 1) * 64 + lane];
#pragma unroll
        for (int m = 0; m < 4; m++) {
            const int pq = p0 + m * 16 + mrow;
            const unsigned int ou =
                *(const unsigned int*)((const char*)offC + ((size_t)pq * 54 + 2 * t3) * 2);
            const __half2 o2 = *(const __half2*)&ou;
            const float oh = __half2float(__low2half(o2));
            const float ov = __half2float(__high2half(o2));
            const float hp  = (float)(hq[m] + j - 1) + oh;
            const float wpf = (float)(wq[m] + k - 1) + ov;
            const float h0f = floorf(hp), w0f = floorf(wpf);
            const int h0 = (int)h0f, w0 = (int)w0f;
            const float lh = hp - h0f, lw = wpf - w0f;
            const bool hv0 = (h0 >= 0) && (h0 < HH);
            const bool hv1 = (h0 >= -1) && (h0 < HH - 1);
            const bool wv0 = (w0 >= 0) && (w0 < WW);
            const bool wv1 = (w0 >= -1) && (w0 < WW - 1);
            const float c00 = (hv0 && wv0) ? (1.f - lh) * (1.f - lw) : 0.f;
            const float c01 = (hv0 && wv1) ? (1.f - lh) * lw : 0.f;
            const float c10 = (hv1 && wv0) ? lh * (1.f - lw) : 0.f;
            const float c11 = (hv1 && wv1) ? lh * lw : 0.f;
            const int h0c = min(max(h0, 0), HH - 1);
            const int h1c = min(max(h0 + 1, 0), HH - 1);
            const int w0c = min(max(w0, 0), WW - 1);
            const int w1c = min(max(w0 + 1, 0), WW - 1);
            F16Frag a00, a01, a10, a11, A;
            a00.v = *(const f16x8*)(xd + (size_t)(h0c * WW + w0c) * CC + kg * 8);
            a01.v = *(const f16x8*)(xd + (size_t)(h0c * WW + w1c) * CC + kg * 8);
            a10.v = *(const f16x8*)(xd + (size_t)(h1c * WW + w0c) * CC + kg * 8);
            a11.v = *(const f16x8*)(xd + (size_t)(h1c * WW + w1c) * CC + kg * 8);
            const __half2 C00 = __float2half2_rn(c00);
            const __half2 C01 = __float2half2_rn(c01);
            const __half2 C10 = __float2half2_rn(c10);
            const __half2 C11 = __float2half2_rn(c11);
#pragma unroll
            for (int r = 0; r < 4; r++) {
                __half2 t = __hmul2(C00, a00.h2[r]);
                t = __hfma2(C01, a01.h2[r], t);
                t = __hfma2(C10, a10.h2[r], t);
                t = __hfma2(C11, a11.h2[r], t);
                A.h2[r] = t;
            }
            acc[m][0] = __builtin_amdgcn_mfma_f32_16x16x32_f16(A.v, b0, acc[m][0], 0, 0, 0);
            acc[m][1] = __builtin_amdgcn_mfma_f32_16x16x32_f16(A.v, b1, acc[m][1], 0, 0, 0);
        }
    }

    // cross-wave reduce (verified D mapping: o=nt*16+mrow, point=m*16+kg*4+reg)
    __shared__ __align__(16) float red[CC * 68];
    if (wave == 1) {
#pragma unroll
        for (int m = 0; m < 4; m++)
#pragma unroll
            for (int nt = 0; nt < 2; nt++) {
                const int o = nt * 16 + mrow;
                *(f32x4*)&red[o * 68 + m * 16 + kg * 4] = acc[m][nt];
            }
    }
    __syncthreads();
    if (wave == 0) {
#pragma unroll
        for (int m = 0; m < 4; m++)
#pragma unroll
            for (int nt = 0; nt < 2; nt++) {
                const int o = nt * 16 + mrow;
                const int idx = o * 68 + m * 16 + kg * 4;
                f32x4 v = *(f32x4*)&red[idx];
                v.x += acc[m][nt].x; v.y += acc[m][nt].y;
                v.z += acc[m][nt].z; v.w += acc[m][nt].w;
                *(f32x4*)&red[idx] = v;
            }
    }
    __syncthreads();
    // copy out: 128 threads, 64 pts x 32 o
    const int pp  = tid & 63;
    const int ob  = tid >> 6;
    if (resid) {
#pragma unroll
        for (int o2 = 0; o2 < 16; o2++) {
            const int o = o2 * 2 + ob;
            float v = red[o * 68 + pp] + bias[o] + resid[(size_t)o * DHW + p0 + pp];
            outp[(size_t)o * DHW + p0 + pp] = v;
        }
    } else {
#pragma unroll
        for (int o2 = 0; o2 < 16; o2++) {
            const int o = o2 * 2 + ob;
            outp[(size_t)o * DHW + p0 + pp] = red[o * 68 + pp] + bias[o];
        }
    }
}

extern "C" void kernel_launch(void* const* d_in, const int* in_sizes, int n_in,
                              void* d_out, int out_size, void* d_ws, size_t ws_size,
                              hipStream_t stream) {
    const float* x   = (const float*)d_in[0];
    const float* g1  = (const float*)d_in[1];
    const float* be1 = (const float*)d_in[2];
    const float* g2  = (const float*)d_in[3];
    const float* be2 = (const float*)d_in[4];
    const float* ow1 = (const float*)d_in[5];
    const float* ob1 = (const float*)d_in[6];
    const float* dw1 = (const float*)d_in[7];
    const float* db1 = (const float*)d_in[8];
    const float* ow2 = (const float*)d_in[9];
    const float* ob2 = (const float*)d_in[10];
    const float* dw2 = (const float*)d_in[11];
    const float* db2 = (const float*)d_in[12];
    float* out = (float*)d_out;
    float* ws  = (float*)d_ws;

    // ws layout (float offsets)
    float*    stats = ws;                           // 16
    _Float16* wBo1  = (_Float16*)(ws + 256);        // 55296 h = 27648 f
    _Float16* wBd1  = (_Float16*)(ws + 27904);      // 27648 h = 13824 f
    _Float16* wBo2  = (_Float16*)(ws + 41728);      // 27648 f
    _Float16* wBd2  = (_Float16*)(ws + 69376);      // 13824 f
    __half*   hT    = (__half*)(ws + 83200);        // DHW*32 h = 3538944 f
    __half*   offC  = (__half*)(ws + 3622144);      // DHW*54 h = 5971968 f

    (void)hipMemsetAsync(stats, 0, 16 * sizeof(float), stream);
    pack_w<<<(27 * 4 * 512 + 255) / 256, 256, 0, stream>>>(ow1, wBo1, 54, 4, 27 * 4 * 512);
    pack_w<<<(27 * 2 * 512 + 255) / 256, 256, 0, stream>>>(dw1, wBd1, 32, 2, 27 * 2 * 512);
    pack_w<<<(27 * 4 * 512 + 255) / 256, 256, 0, stream>>>(ow2, wBo2, 54, 4, 27 * 4 * 512);
    pack_w<<<(27 * 2 * 512 + 255) / 256, 256, 0, stream>>>(dw2, wBd2, 32, 2, 27 * 2 * 512);

    // block 1
    gn_stats<<<NG * 32, 256, 0, stream>>>(x, stats + 0);
    gn_apply_T<<<NBLK_G, 256, 0, stream>>>(x, stats + 0, g1, be1, hT);
    offs_mfma<<<NBLK_O, 128, 0, stream>>>(hT, wBo1, ob1, offC);
    deform_mfma<<<NBLK_D, 128, 0, stream>>>(hT, offC, wBd1, db1, nullptr, out);

    // block 2 (input = deform1 output in d_out)
    gn_stats<<<NG * 32, 256, 0, stream>>>(out, stats + 8);
    gn_apply_T<<<NBLK_G, 256, 0, stream>>>(out, stats + 8, g2, be2, hT);
    offs_mfma<<<NBLK_O, 128, 0, stream>>>(hT, wBo2, ob2, offC);
    deform_mfma<<<NBLK_D, 128, 0, stream>>>(hT, offC, wBd2, db2, x, out);
}

// Round 8
// 367.446 us; speedup vs baseline: 1.4762x; 1.4762x over previous
//
#include <hip/hip_runtime.h>
#include <hip/hip_fp16.h>

// Problem constants (B=1 fixed)
#define CC   32
#define DD   24
#define HH   96
#define WW   96
#define HWC  (HH*WW)        // 9216
#define DHW  (DD*HH*WW)     // 221184
#define NG   4
#define CPG  (CC/NG)        // 8
#define OC1  54
#define GN_EPS 1e-5f

#define NBLK_F (DHW/128)    // 1728 fused blocks (128 pts, 2 waves, 64 pts/wave)
#define CHUNK_F (NBLK_F/8)  // 216
#define NBLK_G (DHW/256)    // 864  (gn_apply)
#define CHUNK_G (NBLK_G/8)  // 108

typedef float  f32x4 __attribute__((ext_vector_type(4)));
typedef _Float16 f16x8 __attribute__((ext_vector_type(8)));
typedef unsigned int u32x4 __attribute__((ext_vector_type(4)));

union F16Frag { f16x8 v; __half2 h2[4]; };

// XCD-chunked swizzle: block b -> XCD b%8 gets a contiguous chunk, so every
// kernel's XCD k owns the SAME 27648-point slice (producer/consumer L2 match).
__device__ __forceinline__ int swz(int bid, int chunk) {
    return (bid % 8) * chunk + (bid / 8);
}

// ---- pack weights into per-tap MFMA B-fragments ----
// src: [O][CC][27] fp32. dst: [tap][nt][lane][e] f16, o=nt*16+(lane&15), c=(lane>>4)*8+e.
__global__ void pack_w(const float* __restrict__ src, _Float16* __restrict__ dst,
                       int O, int NT, int n) {
    int idx = blockIdx.x * 256 + threadIdx.x;
    if (idx >= n) return;
    int e    = idx & 7;
    int lane = (idx >> 3) & 63;
    int nt   = (idx >> 9) % NT;
    int tap  = (idx >> 9) / NT;
    int o = nt * 16 + (lane & 15);
    int c = (lane >> 4) * 8 + e;
    float v = (o < O) ? src[(o * CC + c) * 27 + tap] : 0.f;
    dst[idx] = (_Float16)v;
}

// ---- group-norm stats ----
__global__ void gn_stats(const float* __restrict__ x, float* __restrict__ stats) {
    const int g = blockIdx.x >> 5;
    const int s = blockIdx.x & 31;
    const float4* base = (const float4*)(x + (size_t)g * CPG * DHW);
    const int n4 = CPG * DHW / 4;
    float s1 = 0.f, s2 = 0.f;
    for (int idx = s * 256 + threadIdx.x; idx < n4; idx += 32 * 256) {
        float4 v = base[idx];
        s1 += v.x + v.y + v.z + v.w;
        s2 += v.x * v.x + v.y * v.y + v.z * v.z + v.w * v.w;
    }
    for (int off = 32; off > 0; off >>= 1) {
        s1 += __shfl_down(s1, off);
        s2 += __shfl_down(s2, off);
    }
    __shared__ float ls1[4], ls2[4];
    int wid = threadIdx.x >> 6;
    if ((threadIdx.x & 63) == 0) { ls1[wid] = s1; ls2[wid] = s2; }
    __syncthreads();
    if (threadIdx.x == 0) {
        float a = 0.f, b = 0.f;
        for (int i = 0; i < 4; i++) { a += ls1[i]; b += ls2[i]; }
        atomicAdd(&stats[g * 2 + 0], a);
        atomicAdd(&stats[g * 2 + 1], b);
    }
}

// ---- group-norm apply + relu + transpose to channels-last f16 ----
__global__ void gn_apply_T(const float* __restrict__ x, const float* __restrict__ stats,
                           const float* __restrict__ gamma, const float* __restrict__ beta,
                           __half* __restrict__ yT) {
    const int p = swz(blockIdx.x, CHUNK_G) * 256 + threadIdx.x;
    const float invN = 1.0f / (float)(CPG * DHW);
    float mean[NG], rstd[NG];
#pragma unroll
    for (int g = 0; g < NG; g++) {
        mean[g] = stats[2 * g] * invN;
        float var = stats[2 * g + 1] * invN - mean[g] * mean[g];
        rstd[g] = rsqrtf(var + GN_EPS);
    }
    float vals[CC];
#pragma unroll
    for (int c = 0; c < CC; c++) {
        const int g = c >> 3;
        const float ga = gamma[c] * rstd[g];
        const float be = beta[c] - mean[g] * ga;
        vals[c] = fmaxf(0.f, x[(size_t)c * DHW + p] * ga + be);
    }
    union { __half2 h2[16]; u32x4 q[4]; } u;
#pragma unroll
    for (int c = 0; c < 16; c++) u.h2[c] = __floats2half2_rn(vals[2 * c], vals[2 * c + 1]);
    u32x4* dst = (u32x4*)(yT + (size_t)p * CC);
#pragma unroll
    for (int q = 0; q < 4; q++) dst[q] = u.q[q];
}

// ---- FUSED: offset conv (32->54, MFMA) -> LDS -> deformable conv (MFMA) ----
// Per block: 128 points, 2 waves, each wave owns 64 points end-to-end.
// Verified C/D mapping: o = nt*16 + (lane&15), point = m*16 + (lane>>4)*4 + reg.
#define OPAD 70   // half-elems pad for offset staging (bank-friendly)
__global__ __launch_bounds__(128, 3) void fused_conv(const __half* __restrict__ xT,
                                                     const _Float16* __restrict__ wBo,
                                                     const float* __restrict__ ob,
                                                     const _Float16* __restrict__ wBd,
                                                     const float* __restrict__ db,
                                                     const float* __restrict__ resid,
                                                     float* __restrict__ outp) {
    __shared__ __align__(16) char lds_raw[CC * 132 * 4];   // 16896 B (>= 2*54*70*2)
    __half* offs_lds = (__half*)lds_raw;
    float*  out_lds  = (float*)lds_raw;

    const int tid  = threadIdx.x;
    const int lane = tid & 63;
    const int wave = tid >> 6;
    const int p0   = swz(blockIdx.x, CHUNK_F) * 128;
    const int pw   = p0 + wave * 64;
    const int d    = pw / HWC;        // 128 | 9216, so no d-crossing in a block
    const int rem  = pw % HWC;
    const int mrow = lane & 15;
    const int kg   = lane >> 4;
    const int wbase = wave * (OC1 * OPAD);

    int hq[4], wq[4];
#pragma unroll
    for (int m = 0; m < 4; m++) {
        int rr = rem + m * 16 + mrow;
        hq[m] = rr / WW; wq[m] = rr % WW;
    }

    // ================= Phase A: offset conv, acc_o[m][nt] =================
    f32x4 aco[4][4];
#pragma unroll
    for (int m = 0; m < 4; m++)
#pragma unroll
        for (int n = 0; n < 4; n++) aco[m][n] = (f32x4){0.f, 0.f, 0.f, 0.f};

    const f16x8* wbo8 = (const f16x8*)wBo;

#pragma unroll 1
    for (int i = 0; i < 3; i++) {
        const int dd = d + i - 1;
        if ((unsigned)dd >= DD) continue;
        const __half* xd = xT + (size_t)dd * HWC * CC;
#pragma unroll 3
        for (int jk = 0; jk < 9; jk++) {
            const int j = jk / 3, k = jk % 3, tap = i * 9 + jk;
            const f16x8 b0 = wbo8[(tap * 4 + 0) * 64 + lane];
            const f16x8 b1 = wbo8[(tap * 4 + 1) * 64 + lane];
            const f16x8 b2 = wbo8[(tap * 4 + 2) * 64 + lane];
            const f16x8 b3 = wbo8[(tap * 4 + 3) * 64 + lane];
            f16x8 a[4];
#pragma unroll
            for (int m = 0; m < 4; m++) {
                const int hh = hq[m] + j - 1;
                const int ww = wq[m] + k - 1;
                a[m] = (f16x8){0, 0, 0, 0, 0, 0, 0, 0};
                if ((unsigned)hh < HH && (unsigned)ww < WW)
                    a[m] = *(const f16x8*)(xd + (size_t)(hh * WW + ww) * CC + kg * 8);
            }
#pragma unroll
            for (int m = 0; m < 4; m++) {
                aco[m][0] = __builtin_amdgcn_mfma_f32_16x16x32_f16(a[m], b0, aco[m][0], 0, 0, 0);
                aco[m][1] = __builtin_amdgcn_mfma_f32_16x16x32_f16(a[m], b1, aco[m][1], 0, 0, 0);
                aco[m][2] = __builtin_amdgcn_mfma_f32_16x16x32_f16(a[m], b2, aco[m][2], 0, 0, 0);
                aco[m][3] = __builtin_amdgcn_mfma_f32_16x16x32_f16(a[m], b3, aco[m][3], 0, 0, 0);
            }
        }
    }

    // ================= Phase B: stage offsets in LDS (o-major, +bias) ======
    float bo[4];
#pragma unroll
    for (int nt = 0; nt < 4; nt++) {
        const int o = nt * 16 + mrow;
        bo[nt] = (o < OC1) ? ob[o] : 0.f;
    }
#pragma unroll
    for (int m = 0; m < 4; m++) {
#pragma unroll
        for (int nt = 0; nt < 4; nt++) {
            const int o = nt * 16 + mrow;
            if (o < OC1) {
                const int idx = wbase + o * OPAD + m * 16 + kg * 4;
                __half2 lo = __floats2half2_rn(aco[m][nt].x + bo[nt], aco[m][nt].y + bo[nt]);
                __half2 hi = __floats2half2_rn(aco[m][nt].z + bo[nt], aco[m][nt].w + bo[nt]);
                *(__half2*)&offs_lds[idx]     = lo;
                *(__half2*)&offs_lds[idx + 2] = hi;
            }
        }
    }
    __syncthreads();

    // ================= Phase C: deformable conv =================
    f32x4 acd[4][2];
#pragma unroll
    for (int m = 0; m < 4; m++) {
        acd[m][0] = (f32x4){0.f, 0.f, 0.f, 0.f};
        acd[m][1] = (f32x4){0.f, 0.f, 0.f, 0.f};
    }

    const f16x8* wbd8 = (const f16x8*)wBd;

#pragma unroll 1
    for (int i = 0; i < 3; i++) {
        const int dd = d + i - 1;
        if ((unsigned)dd >= DD) continue;   // zero-padded depth
        const __half* xd = xT + (size_t)dd * HWC * CC;
#pragma unroll 1
        for (int jk = 0; jk < 9; jk++) {
            const int j = jk / 3, k = jk % 3, tap = i * 9 + jk;
            const f16x8 b0 = wbd8[(tap * 2 + 0) * 64 + lane];
            const f16x8 b1 = wbd8[(tap * 2 + 1) * 64 + lane];
            // batch 1: offsets (LDS) -> addresses + coeffs for all 4 m
            int i00[4], i01[4], i10[4], i11[4];
            float c00[4], c01[4], c10[4], c11[4];
#pragma unroll
            for (int m = 0; m < 4; m++) {
                const int ptl = m * 16 + mrow;
                const float oh = __half2float(offs_lds[wbase + (2 * tap + 0) * OPAD + ptl]);
                const float ov = __half2float(offs_lds[wbase + (2 * tap + 1) * OPAD + ptl]);
                const float hp  = (float)(hq[m] + j - 1) + oh;
                const float wpf = (float)(wq[m] + k - 1) + ov;
                const float h0f = floorf(hp), w0f = floorf(wpf);
                const int h0 = (int)h0f, w0 = (int)w0f;
                const float lh = hp - h0f, lw = wpf - w0f;
                const bool hv0 = (h0 >= 0) && (h0 < HH);
                const bool hv1 = (h0 >= -1) && (h0 < HH - 1);
                const bool wv0 = (w0 >= 0) && (w0 < WW);
                const bool wv1 = (w0 >= -1) && (w0 < WW - 1);
                c00[m] = (hv0 && wv0) ? (1.f - lh) * (1.f - lw) : 0.f;
                c01[m] = (hv0 && wv1) ? (1.f - lh) * lw : 0.f;
                c10[m] = (hv1 && wv0) ? lh * (1.f - lw) : 0.f;
                c11[m] = (hv1 && wv1) ? lh * lw : 0.f;
                const int h0c = min(max(h0, 0), HH - 1);
                const int h1c = min(max(h0 + 1, 0), HH - 1);
                const int w0c = min(max(w0, 0), WW - 1);
                const int w1c = min(max(w0 + 1, 0), WW - 1);
                i00[m] = h0c * WW + w0c;
                i01[m] = h0c * WW + w1c;
                i10[m] = h1c * WW + w0c;
                i11[m] = h1c * WW + w1c;
            }
            // batch 2: gathers + blend + MFMA
#pragma unroll
            for (int m = 0; m < 4; m++) {
                F16Frag a00, a01, a10, a11, A;
                a00.v = *(const f16x8*)(xd + (size_t)i00[m] * CC + kg * 8);
                a01.v = *(const f16x8*)(xd + (size_t)i01[m] * CC + kg * 8);
                a10.v = *(const f16x8*)(xd + (size_t)i10[m] * CC + kg * 8);
                a11.v = *(const f16x8*)(xd + (size_t)i11[m] * CC + kg * 8);
                const __half2 C00 = __float2half2_rn(c00[m]);
                const __half2 C01 = __float2half2_rn(c01[m]);
                const __half2 C10 = __float2half2_rn(c10[m]);
                const __half2 C11 = __float2half2_rn(c11[m]);
#pragma unroll
                for (int r = 0; r < 4; r++) {
                    __half2 t = __hmul2(C00, a00.h2[r]);
                    t = __hfma2(C01, a01.h2[r], t);
                    t = __hfma2(C10, a10.h2[r], t);
                    t = __hfma2(C11, a11.h2[r], t);
                    A.h2[r] = t;
                }
                acd[m][0] = __builtin_amdgcn_mfma_f32_16x16x32_f16(A.v, b0, acd[m][0], 0, 0, 0);
                acd[m][1] = __builtin_amdgcn_mfma_f32_16x16x32_f16(A.v, b1, acd[m][1], 0, 0, 0);
            }
        }
    }
    __syncthreads();   // offsets dead; reuse LDS for output staging

    // ================= Phase D: stage + coalesced copy-out =================
#pragma unroll
    for (int m = 0; m < 4; m++)
#pragma unroll
        for (int nt = 0; nt < 2; nt++) {
            const int o = nt * 16 + mrow;
            *(f32x4*)&out_lds[o * 132 + wave * 64 + m * 16 + kg * 4] = acd[m][nt];
        }
    __syncthreads();
    if (resid) {
#pragma unroll 1
        for (int o = 0; o < CC; o++) {
            float v = out_lds[o * 132 + tid] + db[o] + resid[(size_t)o * DHW + p0 + tid];
            outp[(size_t)o * DHW + p0 + tid] = v;
        }
    } else {
#pragma unroll 1
        for (int o = 0; o < CC; o++)
            outp[(size_t)o * DHW + p0 + tid] = out_lds[o * 132 + tid] + db[o];
    }
}

extern "C" void kernel_launch(void* const* d_in, const int* in_sizes, int n_in,
                              void* d_out, int out_size, void* d_ws, size_t ws_size,
                              hipStream_t stream) {
    const float* x   = (const float*)d_in[0];
    const float* g1  = (const float*)d_in[1];
    const float* be1 = (const float*)d_in[2];
    const float* g2  = (const float*)d_in[3];
    const float* be2 = (const float*)d_in[4];
    const float* ow1 = (const float*)d_in[5];
    const float* ob1 = (const float*)d_in[6];
    const float* dw1 = (const float*)d_in[7];
    const float* db1 = (const float*)d_in[8];
    const float* ow2 = (const float*)d_in[9];
    const float* ob2 = (const float*)d_in[10];
    const float* dw2 = (const float*)d_in[11];
    const float* db2 = (const float*)d_in[12];
    float* out = (float*)d_out;
    float* ws  = (float*)d_ws;

    // ws layout (float offsets)
    float*    stats = ws;                           // 16
    _Float16* wBo1  = (_Float16*)(ws + 256);        // 55296 h = 27648 f
    _Float16* wBd1  = (_Float16*)(ws + 27904);      // 27648 h = 13824 f
    _Float16* wBo2  = (_Float16*)(ws + 41728);      // 27648 f
    _Float16* wBd2  = (_Float16*)(ws + 69376);      // 13824 f
    __half*   hT    = (__half*)(ws + 83200);        // DHW*32 h = 3538944 f

    (void)hipMemsetAsync(stats, 0, 16 * sizeof(float), stream);
    pack_w<<<(27 * 4 * 512 + 255) / 256, 256, 0, stream>>>(ow1, wBo1, 54, 4, 27 * 4 * 512);
    pack_w<<<(27 * 2 * 512 + 255) / 256, 256, 0, stream>>>(dw1, wBd1, 32, 2, 27 * 2 * 512);
    pack_w<<<(27 * 4 * 512 + 255) / 256, 256, 0, stream>>>(ow2, wBo2, 54, 4, 27 * 4 * 512);
    pack_w<<<(27 * 2 * 512 + 255) / 256, 256, 0, stream>>>(dw2, wBd2, 32, 2, 27 * 2 * 512);

    // block 1
    gn_stats<<<NG * 32, 256, 0, stream>>>(x, stats + 0);
    gn_apply_T<<<NBLK_G, 256, 0, stream>>>(x, stats + 0, g1, be1, hT);
    fused_conv<<<NBLK_F, 128, 0, stream>>>(hT, wBo1, ob1, wBd1, db1, nullptr, out);

    // block 2 (input = block-1 output in d_out)
    gn_stats<<<NG * 32, 256, 0, stream>>>(out, stats + 8);
    gn_apply_T<<<NBLK_G, 256, 0, stream>>>(out, stats + 8, g2, be2, hT);
    fused_conv<<<NBLK_F, 128, 0, stream>>>(hT, wBo2, ob2, wBd2, db2, x, out);
}